// Round 1
// baseline (1379.424 us; speedup 1.0000x reference)
//
#include <hip/hip_runtime.h>

#define NBINS 513
#define TFRAMES 2048
#define NB 32
#define WIN 1024
#define HOP 256
#define PADT 384
#define OUT_PER_B 524288
#define SPAN 8192
#define SPANS_PER_B (OUT_PER_B / SPAN)  /* 64 */

// One block = one 8192-sample output span of one batch element.
// Computes the ~37 frames overlapping the span: load spectrum column,
// half-size trick -> 512-pt complex IFFT (Stockham, LDS ping-pong),
// window + overlap-add into LDS, then env-divide and store.
__global__ __launch_bounds__(256) void istft_kernel(
    const float* __restrict__ sr, const float* __restrict__ si,
    const float* __restrict__ wnd, float* __restrict__ out)
{
    __shared__ float2 bufA[512];
    __shared__ float2 bufB[512];
    __shared__ float2 xs[512];
    __shared__ float2 ph[512];   // ph[m] = e^{+2*pi*i*m/1024}
    __shared__ float  win[WIN];
    __shared__ float  ola[SPAN];
    __shared__ float  x512re;

    const int tid  = threadIdx.x;
    const int b    = blockIdx.x / SPANS_PER_B;
    const int span = blockIdx.x % SPANS_PER_B;
    const int s0   = span * SPAN;
    const int p0   = s0 + PADT;          // padded-domain start of this span

    // ---- tables ----
    for (int m = tid; m < 512; m += 256) {
        float ang = (float)(6.283185307179586 / 1024.0) * (float)m;
        float sv, cv;
        sincosf(ang, &sv, &cv);
        ph[m] = make_float2(cv, sv);
    }
    for (int m = tid; m < WIN; m += 256) win[m] = wnd[m];
    for (int m = tid; m < SPAN; m += 256) ola[m] = 0.0f;
    __syncthreads();

    // frames overlapping [p0, p0+SPAN)
    int jmin = ((p0 - WIN) >> 8) + 1; if (jmin < 0) jmin = 0;
    int jmax = (p0 + SPAN - 1) >> 8;  if (jmax > TFRAMES - 1) jmax = TFRAMES - 1;

    for (int j = jmin; j <= jmax; ++j) {
        // ---- load spectrum column t=j (strided; L2/L3 amortizes across frames) ----
        {
            const size_t base = ((size_t)b * NBINS) * TFRAMES + (size_t)j;
            const int k0 = tid, k1 = tid + 256;
            float re0 = sr[base + (size_t)k0 * TFRAMES];
            // irfft ignores Im(X[0]) and Im(X[512]) -> zero them
            float im0 = (k0 == 0) ? 0.0f : si[base + (size_t)k0 * TFRAMES];
            xs[k0] = make_float2(re0, im0);
            float re1 = sr[base + (size_t)k1 * TFRAMES];
            float im1 = si[base + (size_t)k1 * TFRAMES];
            xs[k1] = make_float2(re1, im1);
            if (tid == 0) x512re = sr[base + (size_t)512 * TFRAMES];
        }
        __syncthreads();

        // ---- half-size trick: Z[k] = E[k] + i*O[k] ----
        for (int k = tid; k < 512; k += 256) {
            float2 Xk = xs[k];
            float2 Xm = (k == 0) ? make_float2(x512re, 0.0f) : xs[512 - k];
            float Ex = 0.5f * (Xk.x + Xm.x);
            float Ey = 0.5f * (Xk.y - Xm.y);
            float Dx = 0.5f * (Xk.x - Xm.x);
            float Dy = 0.5f * (Xk.y + Xm.y);
            float2 w = ph[k];                       // e^{+2pi i k/1024}
            float Ox = Dx * w.x - Dy * w.y;
            float Oy = Dx * w.y + Dy * w.x;
            bufA[k] = make_float2(Ex - Oy, Ey + Ox); // E + i*O
        }
        __syncthreads();

        // ---- 512-pt inverse FFT, 9-stage radix-2 Stockham (autosort) ----
        float2* src = bufA;
        float2* dst = bufB;
        for (int s = 0; s < 9; ++s) {
            const int Ls = 1 << s;
            const int k  = tid & (Ls - 1);
            float2 a  = src[tid];
            float2 bb = src[tid + 256];
            float2 w  = ph[k << (9 - s)];           // e^{+2pi i k/(2Ls)}
            float wbx = bb.x * w.x - bb.y * w.y;
            float wby = bb.x * w.y + bb.y * w.x;
            const int o = ((tid >> s) << (s + 1)) + k;
            dst[o]      = make_float2(a.x + wbx, a.y + wby);
            dst[o + Ls] = make_float2(a.x - wbx, a.y - wby);
            __syncthreads();
            float2* tmp = src; src = dst; dst = tmp;
        }
        // src now holds z[n]; x[2n]=Re z[n]/512, x[2n+1]=Im z[n]/512

        // ---- window + overlap-add into LDS span buffer ----
        const int basep = j * HOP - p0;
        for (int n = tid; n < 512; n += 256) {
            float2 z = src[n];
            const int n2 = 2 * n;
            const int q0 = basep + n2;
            const int q1 = q0 + 1;
            if ((unsigned)q0 < SPAN) ola[q0] += z.x * (1.0f / 512.0f) * win[n2];
            if ((unsigned)q1 < SPAN) ola[q1] += z.y * (1.0f / 512.0f) * win[n2 + 1];
        }
        __syncthreads();
    }

    // ---- envelope divide + store ----
    for (int sl = tid; sl < SPAN; sl += 256) {
        const int p = p0 + sl;
        int lo = ((p - WIN) >> 8) + 1; if (lo < 0) lo = 0;
        int hi = p >> 8;               if (hi > TFRAMES - 1) hi = TFRAMES - 1;
        float env = 0.0f;
        for (int jj = lo; jj <= hi; ++jj) {
            float wv = win[p - jj * HOP];
            env += wv * wv;
        }
        out[(size_t)b * OUT_PER_B + (size_t)(s0 + sl)] = ola[sl] / env;
    }
}

extern "C" void kernel_launch(void* const* d_in, const int* in_sizes, int n_in,
                              void* d_out, int out_size, void* d_ws, size_t ws_size,
                              hipStream_t stream) {
    const float* sr  = (const float*)d_in[0];
    const float* si  = (const float*)d_in[1];
    const float* wnd = (const float*)d_in[2];
    float* out = (float*)d_out;
    dim3 grid(NB * SPANS_PER_B);   // 2048 blocks
    dim3 block(256);
    hipLaunchKernelGGL(istft_kernel, grid, block, 0, stream, sr, si, wnd, out);
}

// Round 2
// 280.533 us; speedup vs baseline: 4.9172x; 4.9172x over previous
//
#include <hip/hip_runtime.h>

#define NBINS 513
#define TFR   2048
#define NB    32
#define WIN   1024
#define HOP   256
#define PADT  384
#define OPB   524288              /* out samples per batch */
#define FR    8                   /* frames per tile/block */
#define TILES (TFR / FR)          /* 256 */
#define OLA_N (FR*HOP + WIN - HOP) /* 2816 */
#define PIDX(i) ((i) + ((i) >> 4)) /* LDS anti-bank-conflict pad */

__device__ __forceinline__ int brev9(int k) { return (int)(__brev((unsigned)k) >> 23); }

__global__ __launch_bounds__(256) void zero_out(float4* __restrict__ o4, int n4) {
    for (int i = blockIdx.x * 256 + threadIdx.x; i < n4; i += gridDim.x * 256)
        o4[i] = make_float4(0.f, 0.f, 0.f, 0.f);
}

// One block = 8 consecutive frames of one batch. Coalesced row-wise staging,
// 8x 512-pt complex IFFT (half-size real trick), windowed OLA in LDS,
// plain-store interior / atomicAdd 768-sample seams into zeroed d_out.
__global__ __launch_bounds__(256) void istft_frames(
    const float* __restrict__ sr, const float* __restrict__ si,
    const float* __restrict__ wnd, float* __restrict__ out)
{
    __shared__ float2 stile[FR][NBINS];   // (re,im) per (frame,bin)   32832 B
    __shared__ float2 fbuf[544];          // padded FFT workspace       4352 B
    __shared__ float2 ph[545];            // e^{+2pi i m/1024}, m<=512  4360 B
    __shared__ float2 ola2[OLA_N / 2];    // OLA accumulator           11264 B

    const int tid = threadIdx.x;
    const int nwg = NB * TILES;           // 8192
    const int bid = blockIdx.x;
    const int swz = (bid & 7) * (nwg >> 3) + (bid >> 3);  // XCD-chunked
    const int b    = swz / TILES;
    const int tile = swz % TILES;
    const int j0   = tile * FR;

    // ---- twiddle table (exact, once per block) ----
    for (int m = tid; m <= 512; m += 256) {
        float sv, cv;
        sincosf(6.283185307179586f * (float)m / 1024.0f, &sv, &cv);
        ph[PIDX(m)] = make_float2(cv, sv);
    }
    for (int m = tid; m < OLA_N / 2; m += 256) ola2[m] = make_float2(0.f, 0.f);

    // ---- coalesced staging: rows = bins (contig along T), 8 floats/row ----
    {
        const size_t base = (size_t)b * NBINS * TFR + (size_t)j0;
        for (int m = tid; m < NBINS * (FR / 2); m += 256) {   // 2052
            const int row = m >> 2;
            const int h   = m & 3;
            const size_t ga = base + (size_t)row * TFR + 2 * h;
            float2 re2 = *(const float2*)(sr + ga);
            float2 im2 = *(const float2*)(si + ga);
            if (row == 0 || row == NBINS - 1) { im2.x = 0.f; im2.y = 0.f; } // irfft ignores these
            stile[2 * h][row]     = make_float2(re2.x, im2.x);
            stile[2 * h + 1][row] = make_float2(re2.y, im2.y);
        }
    }
    __syncthreads();

    for (int f = 0; f < FR; ++f) {
        // ---- half-size trick -> Z, written bit-reversed into fbuf ----
        #pragma unroll
        for (int kk = 0; kk < 2; ++kk) {
            const int k = tid + kk * 256;
            float2 Xk = stile[f][k];
            float2 Xm = stile[f][512 - k];
            float Ex = 0.5f * (Xk.x + Xm.x), Ey = 0.5f * (Xk.y - Xm.y);
            float Dx = 0.5f * (Xk.x - Xm.x), Dy = 0.5f * (Xk.y + Xm.y);
            float2 w = ph[PIDX(k)];                    // e^{+2pi i k/1024}
            float Ox = Dx * w.x - Dy * w.y, Oy = Dx * w.y + Dy * w.x;
            fbuf[PIDX(brev9(k))] = make_float2(Ex - Oy, Ey + Ox);
        }
        __syncthreads();

        // ---- in-place DIT, 9 stages, e^{+} twiddles from table ----
        #pragma unroll
        for (int s = 0; s <= 8; ++s) {
            const int Ls = 1 << s;
            const int k  = tid & (Ls - 1);
            const int i0 = ((tid >> s) << (s + 1)) + k;
            float2 u = fbuf[PIDX(i0)];
            float2 v = fbuf[PIDX(i0 + Ls)];
            float2 w = ph[PIDX(k << (9 - s))];         // e^{+2pi i k/2^{s+1}}
            float tx = v.x * w.x - v.y * w.y;
            float ty = v.x * w.y + v.y * w.x;
            fbuf[PIDX(i0)]      = make_float2(u.x + tx, u.y + ty);
            fbuf[PIDX(i0 + Ls)] = make_float2(u.x - tx, u.y - ty);
            __syncthreads();
        }

        // ---- window + OLA (float2 lanes, conflict-free) ----
        const float sc = 1.0f / 512.0f;
        #pragma unroll
        for (int kk = 0; kk < 2; ++kk) {
            const int n  = tid + kk * 256;
            float2 z = fbuf[PIDX(n)];
            const int m0 = 2 * n, m1 = 2 * n + 1;
            const int q0 = (m0 <= 512) ? m0 : 1024 - m0;
            const int q1 = (m1 <= 512) ? m1 : 1024 - m1;
            float w0 = 0.5f - 0.5f * ph[PIDX(q0)].x;   // hann from twiddle table
            float w1 = 0.5f - 0.5f * ph[PIDX(q1)].x;
            float2 acc = ola2[f * 128 + n];
            acc.x += z.x * sc * w0;
            acc.y += z.y * sc * w1;
            ola2[f * 128 + n] = acc;
        }
        __syncthreads();
    }

    // ---- write out: seams atomic, interior plain ----
    const float* olaf = (const float*)ola2;
    const size_t ob = (size_t)b * OPB;
    const int p_base = j0 * HOP;
    for (int idx = tid; idx < OLA_N; idx += 256) {
        const int oi = p_base + idx - PADT;
        if ((unsigned)oi < (unsigned)OPB) {
            float v = olaf[idx];
            if (idx < WIN - HOP || idx >= FR * HOP) atomicAdd(&out[ob + oi], v);
            else                                    out[ob + oi] = v;
        }
    }
}

// Envelope divide: env is HOP-periodic except near edges.
__global__ __launch_bounds__(256) void env_div(
    const float* __restrict__ wnd, float* __restrict__ out)
{
    __shared__ float win[WIN];
    __shared__ float renv[HOP];           // reciprocal interior envelope
    const int tid = threadIdx.x;
    for (int m = tid; m < WIN; m += 256) win[m] = wnd[m];
    __syncthreads();
    for (int m = tid; m < HOP; m += 256) {
        float e = 0.f;
        #pragma unroll
        for (int r = 0; r < 4; ++r) { float w = win[m + r * HOP]; e += w * w; }
        renv[m] = 1.0f / e;
    }
    __syncthreads();

    float4* o4 = (float4*)out;
    const int total4 = NB * (OPB / 4);
    for (int i = blockIdx.x * 256 + tid; i < total4; i += gridDim.x * 256) {
        float4 v = o4[i];
        const int ib = i & (OPB / 4 - 1);
        const int p0 = ib * 4 + PADT;
        if (p0 >= WIN - HOP && p0 + 3 < OPB) {          // interior: 4 full terms
            v.x *= renv[(p0)     & (HOP - 1)];
            v.y *= renv[(p0 + 1) & (HOP - 1)];
            v.z *= renv[(p0 + 2) & (HOP - 1)];
            v.w *= renv[(p0 + 3) & (HOP - 1)];
        } else {
            float r[4];
            #pragma unroll
            for (int q = 0; q < 4; ++q) {
                const int p = p0 + q;
                int lo = (p >= WIN - HOP) ? ((p - (WIN - HOP)) >> 8) : 0;
                int hi = p >> 8; if (hi > TFR - 1) hi = TFR - 1;
                float e = 0.f;
                for (int j = lo; j <= hi; ++j) { float w = win[p - j * HOP]; e += w * w; }
                r[q] = e;
            }
            v.x /= r[0]; v.y /= r[1]; v.z /= r[2]; v.w /= r[3];
        }
        o4[i] = v;
    }
}

extern "C" void kernel_launch(void* const* d_in, const int* in_sizes, int n_in,
                              void* d_out, int out_size, void* d_ws, size_t ws_size,
                              hipStream_t stream) {
    const float* sr  = (const float*)d_in[0];
    const float* si  = (const float*)d_in[1];
    const float* wnd = (const float*)d_in[2];
    float* out = (float*)d_out;

    hipLaunchKernelGGL(zero_out, dim3(2048), dim3(256), 0, stream,
                       (float4*)out, NB * (OPB / 4));
    hipLaunchKernelGGL(istft_frames, dim3(NB * TILES), dim3(256), 0, stream,
                       sr, si, wnd, out);
    hipLaunchKernelGGL(env_div, dim3(2048), dim3(256), 0, stream, wnd, out);
}

// Round 4
// 186.578 us; speedup vs baseline: 7.3933x; 1.5036x over previous
//
#include <hip/hip_runtime.h>

#define NBINS 513
#define TFR   2048
#define NB    32
#define WIN   1024
#define HOP   256
#define PADT  384
#define OPB   524288
#define FR    8
#define TILES (TFR / FR)            /* 256 */
#define OLA_N (FR*HOP + WIN - HOP)  /* 2816 */
#define FSTRIDE 545                 /* float2 per frame row, padded */
#define PIDX(i) ((i) + ((i) >> 4))
#define C45 0.70710678118654752f

__device__ __forceinline__ float2 cadd(float2 a, float2 b){ return make_float2(a.x+b.x, a.y+b.y); }
__device__ __forceinline__ float2 csub(float2 a, float2 b){ return make_float2(a.x-b.x, a.y-b.y); }
__device__ __forceinline__ float2 cmul(float2 a, float2 b){ return make_float2(a.x*b.x - a.y*b.y, a.x*b.y + a.y*b.x); }

// In-place radix-8 DIF butterfly (e^{+} kernel), span L. Natural input,
// digit-reversed output across the 3 stages L=64,8,1.
template<int L>
__device__ __forceinline__ void fft_stage(float2* __restrict__ row,
                                          const float2* __restrict__ ph, int i)
{
    const int k    = i & (L - 1);
    const int base = ((i & ~(L - 1)) << 3) + k;   // (i/L)*8L + k

    float2 u0 = row[PIDX(base + 0*L)];
    float2 u1 = row[PIDX(base + 1*L)];
    float2 u2 = row[PIDX(base + 2*L)];
    float2 u3 = row[PIDX(base + 3*L)];
    float2 u4 = row[PIDX(base + 4*L)];
    float2 u5 = row[PIDX(base + 5*L)];
    float2 u6 = row[PIDX(base + 6*L)];
    float2 u7 = row[PIDX(base + 7*L)];

    float2 s0=cadd(u0,u4), t0=csub(u0,u4);
    float2 s1=cadd(u1,u5), t1=csub(u1,u5);
    float2 s2=cadd(u2,u6), t2=csub(u2,u6);
    float2 s3=cadd(u3,u7), t3=csub(u3,u7);
    t1 = make_float2(C45*(t1.x - t1.y),  C45*(t1.x + t1.y));   // *W8^1 = (c+ic)
    t2 = make_float2(-t2.y, t2.x);                              // *i
    t3 = make_float2(-C45*(t3.x + t3.y), C45*(t3.x - t3.y));   // *W8^3 = (-c+ic)

    float2 p0=cadd(s0,s2), p2=csub(s0,s2);
    float2 p1=cadd(s1,s3), p3=csub(s1,s3); p3 = make_float2(-p3.y, p3.x);
    float2 q0=cadd(t0,t2), q2=csub(t0,t2);
    float2 q1=cadd(t1,t3), q3=csub(t1,t3); q3 = make_float2(-q3.y, q3.x);

    float2 v0=cadd(p0,p1), v4=csub(p0,p1);
    float2 v2=cadd(p2,p3), v6=csub(p2,p3);
    float2 v1=cadd(q0,q1), v5=csub(q0,q1);
    float2 v3=cadd(q2,q3), v7=csub(q2,q3);

    if (L > 1) {   // span twiddles W_{8L}^{+qk}, generated iteratively
        const float2 w1 = ph[k * (128 / L)];
        float2 wq = w1;
        v1 = cmul(v1, wq);
        wq = cmul(wq, w1); v2 = cmul(v2, wq);
        wq = cmul(wq, w1); v3 = cmul(v3, wq);
        wq = cmul(wq, w1); v4 = cmul(v4, wq);
        wq = cmul(wq, w1); v5 = cmul(v5, wq);
        wq = cmul(wq, w1); v6 = cmul(v6, wq);
        wq = cmul(wq, w1); v7 = cmul(v7, wq);
    }
    row[PIDX(base + 0*L)] = v0;
    row[PIDX(base + 1*L)] = v1;
    row[PIDX(base + 2*L)] = v2;
    row[PIDX(base + 3*L)] = v3;
    row[PIDX(base + 4*L)] = v4;
    row[PIDX(base + 5*L)] = v5;
    row[PIDX(base + 6*L)] = v6;
    row[PIDX(base + 7*L)] = v7;
}

__global__ __launch_bounds__(256) void zero_seams(float* __restrict__ out)
{
    const int total = NB * 257 * 768;
    for (int id = blockIdx.x * 256 + threadIdx.x; id < total; id += gridDim.x * 256) {
        const int q = id % 768;
        const int r = id / 768;
        const int s = r % 257;
        const int bb = r / 257;
        const int p  = s * 2048 + q;
        const int oi = p - PADT;
        if ((unsigned)oi < (unsigned)OPB) out[(size_t)bb * OPB + oi] = 0.f;
    }
}

// One block = 8 consecutive frames of one batch. Staged coalesced load,
// in-place half-size trick + radix-8 DIF x3 (all 8 frames concurrently),
// OLA in LDS (frame-invariant cell ownership), fused env-divide on interior
// stores, atomics on seams.
__global__ __launch_bounds__(256) void istft8(
    const float* __restrict__ sr, const float* __restrict__ si,
    float* __restrict__ out)
{
    __shared__ float2 stile[FR * FSTRIDE];   // 34880 B
    __shared__ float2 ph[513];               //  4104 B  e^{+2pi i m/1024}
    __shared__ float2 olab2[OLA_N / 2];      // 11264 B
    __shared__ float  renv[HOP];             //  1024 B

    const int tid = threadIdx.x;
    const int bid = blockIdx.x;
    const int nwg = NB * TILES;                           // 8192
    const int swz = (bid & 7) * (nwg >> 3) + (bid >> 3);  // XCD-chunked (bijective)
    const int b    = swz / TILES;
    const int tile = swz % TILES;
    const int j0   = tile * FR;

    for (int m = tid; m <= 512; m += 256) {
        float sv, cv;
        sincosf(6.283185307179586f / 1024.0f * (float)m, &sv, &cv);
        ph[m] = make_float2(cv, sv);
    }
    for (int m = tid; m < OLA_N / 2; m += 256) olab2[m] = make_float2(0.f, 0.f);

    // coalesced staging: 8 floats (4 float2) per bin row
    {
        const size_t base = (size_t)b * NBINS * TFR + (size_t)j0;
        for (int m = tid; m < NBINS * (FR / 2); m += 256) {   // 2052
            const int row = m >> 2;
            const int h   = m & 3;
            const size_t ga = base + (size_t)row * TFR + 2 * h;
            float2 re2 = *(const float2*)(sr + ga);
            float2 im2 = *(const float2*)(si + ga);
            if (row == 0 || row == NBINS - 1) { im2.x = 0.f; im2.y = 0.f; } // irfft ignores
            stile[(2*h)   * FSTRIDE + PIDX(row)] = make_float2(re2.x, im2.x);
            stile[(2*h+1) * FSTRIDE + PIDX(row)] = make_float2(re2.y, im2.y);
        }
    }
    __syncthreads();

    // interior envelope reciprocal (HOP-periodic, 4 full hann^2 terms)
    {
        float e = 0.f;
        #pragma unroll
        for (int r = 0; r < 4; ++r) {
            const int m  = tid + r * HOP;
            const int mm = (m <= 512) ? m : 1024 - m;
            const float w = 0.5f - 0.5f * ph[mm].x;
            e += w * w;
        }
        renv[tid] = 1.0f / e;
    }

    // half-size trick, in place (pair (k, 512-k) per thread; disjoint across threads)
    for (int f = 0; f < FR; ++f) {
        float2* row = &stile[f * FSTRIDE];
        const int k = tid;
        float2 Xk = row[PIDX(k)];
        float2 Xm = row[PIDX(512 - k)];
        float Ex = 0.5f*(Xk.x + Xm.x), Ey = 0.5f*(Xk.y - Xm.y);
        float Dx = 0.5f*(Xk.x - Xm.x), Dy = 0.5f*(Xk.y + Xm.y);
        float2 w = ph[k];
        float Ox = Dx*w.x - Dy*w.y, Oy = Dx*w.y + Dy*w.x;
        row[PIDX(k)]       = make_float2(Ex - Oy, Ey + Ox);   // Z[k]
        row[PIDX(512 - k)] = make_float2(Ex + Oy, Ox - Ey);   // Z[512-k] (k>0); k=0 write lands at unused slot 512
        if (tid == 0) {
            float2 Xc = row[PIDX(256)];
            row[PIDX(256)] = make_float2(Xc.x, -Xc.y);        // Z[256] = conj(X[256])
        }
    }
    __syncthreads();

    // 512-pt IFFT: 3 radix-8 DIF stages, 8 frames concurrently
    {
        const int f  = tid >> 5;
        float2* row  = &stile[f * FSTRIDE];
        const int i0 = tid & 31;
        fft_stage<64>(row, ph, i0);
        fft_stage<64>(row, ph, i0 + 32);
        __syncthreads();
        fft_stage<8>(row, ph, i0);
        fft_stage<8>(row, ph, i0 + 32);
        __syncthreads();
        fft_stage<1>(row, ph, i0);
        fft_stage<1>(row, ph, i0 + 32);
        __syncthreads();
    }

    // windowed OLA. Frame-invariant ownership: thread handles n such that
    // cell c2 = f*128+n has c2&255 == tid  ->  no cross-thread RMW, no races.
    {
        const float sc = 1.0f / 512.0f;
        for (int f = 0; f < FR; ++f) {
            const float2* row = &stile[f * FSTRIDE];
            const int nb0 = (tid + ((f & 1) << 7)) & 255;
            #pragma unroll
            for (int kk = 0; kk < 2; ++kk) {
                const int n = nb0 + kk * 256;
                const int j = ((n & 7) << 6) | (n & 56) | (n >> 6);  // drev8
                float2 z = row[PIDX(j)];
                const int m0  = 2 * n;
                const int mm0 = (m0 <= 512) ? m0 : 1024 - m0;
                const int m1  = m0 + 1;
                const int mm1 = (m1 <= 512) ? m1 : 1024 - m1;
                const float w0 = 0.5f - 0.5f * ph[mm0].x;
                const float w1 = 0.5f - 0.5f * ph[mm1].x;
                const int c2 = f * 128 + n;       // c2 & 255 == tid
                float2 acc = olab2[c2];
                acc.x += z.x * (sc * w0);
                acc.y += z.y * (sc * w1);
                olab2[c2] = acc;
            }
        }
    }
    __syncthreads();

    // store: interior = env-divided plain store; seams = raw atomicAdd
    {
        const float* olaf = (const float*)olab2;
        const size_t ob = (size_t)b * OPB;
        const int pb = j0 * HOP;
        for (int idx = tid; idx < OLA_N; idx += 256) {
            const int p  = pb + idx;
            const int oi = p - PADT;
            if ((unsigned)oi < (unsigned)OPB) {
                const float v = olaf[idx];
                if ((p & 2047) < 768) atomicAdd(&out[ob + oi], v);
                else                  out[ob + oi] = v * renv[p & 255];
            }
        }
    }
}

__global__ __launch_bounds__(256) void seam_fix(float* __restrict__ out)
{
    __shared__ float wsq[WIN];
    const int tid = threadIdx.x;
    for (int m = tid; m < WIN; m += 256) {
        float sv, cv;
        sincosf(6.283185307179586f / 1024.0f * (float)m, &sv, &cv);
        const float w = 0.5f - 0.5f * cv;
        wsq[m] = w * w;
    }
    __syncthreads();

    const int total = NB * 257 * 768;
    for (int id = blockIdx.x * 256 + tid; id < total; id += gridDim.x * 256) {
        const int q = id % 768;
        const int r = id / 768;
        const int s = r % 257;
        const int bb = r / 257;
        const int p  = s * 2048 + q;
        const int oi = p - PADT;
        if ((unsigned)oi < (unsigned)OPB) {
            int jlo = (p - 768) >> 8; if (jlo < 0) jlo = 0;
            int jhi = p >> 8;         if (jhi > TFR - 1) jhi = TFR - 1;
            float e = 0.f;
            for (int j = jlo; j <= jhi; ++j) e += wsq[p - j * HOP];
            out[(size_t)bb * OPB + oi] /= e;
        }
    }
}

extern "C" void kernel_launch(void* const* d_in, const int* in_sizes, int n_in,
                              void* d_out, int out_size, void* d_ws, size_t ws_size,
                              hipStream_t stream) {
    const float* sr = (const float*)d_in[0];
    const float* si = (const float*)d_in[1];
    float* out = (float*)d_out;

    hipLaunchKernelGGL(zero_seams, dim3(2048), dim3(256), 0, stream, out);
    hipLaunchKernelGGL(istft8, dim3(NB * TILES), dim3(256), 0, stream, sr, si, out);
    hipLaunchKernelGGL(seam_fix, dim3(2048), dim3(256), 0, stream, out);
}